// Round 8
// baseline (3017.135 us; speedup 1.0000x reference)
//
#include <hip/hip_runtime.h>
#include <hip/hip_bf16.h>

typedef unsigned short u16;
typedef unsigned int u32;
typedef unsigned long long u64;
typedef __attribute__((ext_vector_type(8))) short short8;
typedef __attribute__((ext_vector_type(4))) float f32x4;
typedef __attribute__((ext_vector_type(4))) unsigned short u16x4;

constexpr int Bb = 64, Tt = 512, INi = 1024, Hh = 1024, Cc = 512;

__device__ inline u16 f2bf(float f){
  unsigned u = __float_as_uint(f);
  u += 0x7FFF + ((u >> 16) & 1);          // RTNE
  return (u16)(u >> 16);
}
__device__ inline float bf2f(u16 v){ return __uint_as_float(((unsigned)v) << 16); }

// ---------------- f32 -> bf16 bulk convert ----------------
__global__ void cvt_kernel(const float* __restrict__ in, u16* __restrict__ outp, long n4){
  long i = (long)blockIdx.x * blockDim.x + threadIdx.x;
  const long stride = (long)gridDim.x * blockDim.x;
  for (; i < n4; i += stride){
    float4 v = reinterpret_cast<const float4*>(in)[i];
    u16x4 o = { f2bf(v.x), f2bf(v.y), f2bf(v.z), f2bf(v.w) };
    reinterpret_cast<u16x4*>(outp)[i] = o;
  }
}

// ---------------- init tagged h0 (buffer0, tag 0) + sentinel (buffer1) ----------------
__global__ __launch_bounds__(256) void hinit_kernel(const float* __restrict__ h0,
                                                    float* __restrict__ Hf){
  const int i = blockIdx.x * blockDim.x + threadIdx.x;   // 0..32767, 2 f32 each
  float a = h0[2*i], b = h0[2*i + 1];
  u32 w0 = ((u32)f2bf(a) << 16);
  u32 w1 = ((u32)f2bf(b) << 16);
  u64 p = (u64)w0 | ((u64)w1 << 32);
  __hip_atomic_store((u64*)Hf + i, p, __ATOMIC_RELAXED, __HIP_MEMORY_SCOPE_AGENT);
  __hip_atomic_store((u64*)(Hf + (long)Bb*Hh) + i, 0xFFFFFFFFFFFFFFFFull,
                     __ATOMIC_RELAXED, __HIP_MEMORY_SCOPE_AGENT);
}

// ---------------- bf16 NT GEMM: C[m][n] = sum_k A[m][k]*B[n][k] ----------------
__global__ __launch_bounds__(256) void gemm_nt(
  const u16* __restrict__ A, const u16* __restrict__ Bm,
  float* __restrict__ Cf, u16* __restrict__ Cb, const float* __restrict__ bias,
  int M, int N, int K, int write_bf16)
{
  __shared__ u16 Als[128][32];
  __shared__ u16 Bls[128][32];
  const int tid  = threadIdx.x;
  const long m0  = (long)blockIdx.x * 128;
  const long n0  = (long)blockIdx.y * 128;
  const int wave = tid >> 6, lane = tid & 63;
  const int wm = (wave >> 1) * 64, wn = (wave & 1) * 64;
  const int r0 = tid >> 2, c8 = (tid & 3) * 8;
  const int fr = lane & 15, kq = (lane >> 4) * 8;
  f32x4 acc[4][4] = {};
#pragma unroll 1
  for (int k0 = 0; k0 < K; k0 += 32){
    *(short8*)(&Als[r0][c8])      = *(const short8*)(&A[(m0 + r0)*K + k0 + c8]);
    *(short8*)(&Als[r0 + 64][c8]) = *(const short8*)(&A[(m0 + r0 + 64)*K + k0 + c8]);
    *(short8*)(&Bls[r0][c8])      = *(const short8*)(&Bm[(n0 + r0)*K + k0 + c8]);
    *(short8*)(&Bls[r0 + 64][c8]) = *(const short8*)(&Bm[(n0 + r0 + 64)*K + k0 + c8]);
    __syncthreads();
    short8 af[4], bfv[4];
#pragma unroll
    for (int i = 0; i < 4; i++) af[i]  = *(const short8*)(&Als[wm + i*16 + fr][kq]);
#pragma unroll
    for (int i = 0; i < 4; i++) bfv[i] = *(const short8*)(&Bls[wn + i*16 + fr][kq]);
#pragma unroll
    for (int mi = 0; mi < 4; mi++)
#pragma unroll
      for (int ni = 0; ni < 4; ni++)
        acc[mi][ni] = __builtin_amdgcn_mfma_f32_16x16x32_bf16(af[mi], bfv[ni], acc[mi][ni], 0, 0, 0);
    __syncthreads();
  }
  const int rq = (lane >> 4) * 4;
#pragma unroll
  for (int mi = 0; mi < 4; mi++)
#pragma unroll
    for (int ni = 0; ni < 4; ni++)
#pragma unroll
      for (int r = 0; r < 4; r++){
        long gm = m0 + wm + mi*16 + rq + r;
        long gn = n0 + wn + ni*16 + fr;
        float v = acc[mi][ni][r];
        if (write_bf16) Cb[gm*N + gn] = f2bf(v + bias[gn]);
        else            Cf[gm*N + gn] = v;
      }
}

// ---------------- in-place EMA over time: xcb <- c_t (bf16), cT f32 ----------------
__global__ __launch_bounds__(128) void ema_kernel(u16* __restrict__ xcb,
                                                  const float* __restrict__ c0,
                                                  float* __restrict__ cT){
  const int b = blockIdx.x >> 2;
  const int c = ((blockIdx.x & 3) * 128) + threadIdx.x;
  float run = c0[b*Cc + c];
  u16* p = xcb + (long)b*Tt*Cc + c;
#pragma unroll 1
  for (int t = 0; t < Tt; t += 8){
    u16 v[8];
#pragma unroll
    for (int u = 0; u < 8; u++) v[u] = p[(long)(t + u)*Cc];
#pragma unroll
    for (int u = 0; u < 8; u++){
      run = 0.05f*run + 0.95f*bf2f(v[u]);
      p[(long)(t + u)*Cc] = f2bf(run);
    }
  }
  cT[b*Cc + c] = run;
}

// ---------------- persistent recurrent kernel: hybrid tag/flag sync ----------------
// 32 blocks: block = (batch-group of 16) x (h-column-group of 128).
// 512 threads = 8 waves, K-split 8x128. Round-3 skeleton (1760us proven).
// h transmitted as tagged f32: high 16 = RTNE bf16 (exact numerics), low 10 =
// step tag. FAST path: bounded spin on the data's own tags (readiness+data in
// one LLC RT, skips flag-detect RT). FALLBACK (bounded, proven): round-3 flag
// poll + fresh reload. Hang-proof: worst case == round-3 protocol.
__global__ __launch_bounds__(512, 2) void recur_kernel(
  const u16* __restrict__ Vhb, float* __restrict__ Hf,
  float* __restrict__ outp, float* __restrict__ hT, int* __restrict__ flags)
{
  const int tid = threadIdx.x;
  const int wv = tid >> 6, lane = tid & 63;
  const int bid = blockIdx.x;
  const int b0 = (bid >> 3) * 16;     // batch rows
  const int n0 = (bid & 7) * 128;     // h columns owned (output)
  const int fr = lane & 15, kq = (lane >> 4) * 8;
  const int rq = (lane >> 4) * 4;
  const int kbase = wv * 128;         // this wave's k-slice
  const int sw_w = rq << 1;           // write-side XOR swizzle

  // Vh fragments (compiler keeps in VGPR/AGPR as it sees fit; round-3 proven)
  short8 wf[8][4];
#pragma unroll
  for (int nf = 0; nf < 8; nf++)
#pragma unroll
    for (int ks = 0; ks < 4; ks++)
      wf[nf][ks] = *(const short8*)(&Vhb[(long)(n0 + nf*16 + fr)*Hh + kbase + ks*32 + kq]);

  __shared__ float part[8][16][128];  // 64 KiB

  const int row = tid >> 5;           // 0..15
  const int c4  = (tid & 31) * 4;     // 0..124
  const int sw_r = (row & 12) << 1;
  int* pollp  = &flags[((bid & ~7) | wv) * 32];   // producer of my k-slice
  int* myflag = &flags[bid * 32];

#pragma unroll 1
  for (int t = 0; t < Tt; t++){
    // ---- prefetch g = (c@Uc^T)[b,t,:]: HBM latency hides under the wait ----
    const long gaddr = ((long)(b0 + row)*Tt + t)*Hh + n0 + c4;
    const f32x4 g4 = *reinterpret_cast<const f32x4*>(&outp[gaddr]);

    // ---- FAST path: bounded spin on tagged h data (1 LLC RT) ----
    const u64* hp = (const u64*)(Hf + (long)(t & 1)*(Bb*Hh) + (long)(b0 + fr)*Hh + kbase + kq);
    const u32 tag = (u32)t;
    u64 q[16];
    bool ok = false;
#pragma unroll 1
    for (int it = 0; it < 256 && !ok; ++it){
      u32 bad = 0;
#pragma unroll
      for (int ks = 0; ks < 4; ks++)
#pragma unroll
        for (int j = 0; j < 4; j++){
          u64 v = __hip_atomic_load(hp + ks*16 + j, __ATOMIC_RELAXED, __HIP_MEMORY_SCOPE_AGENT);
          q[ks*4 + j] = v;
          bad |= ((u32)v ^ tag) & 0x3FFu;
          bad |= ((u32)(v >> 32) ^ tag) & 0x3FFu;
        }
      ok = __all(bad == 0);
    }
    // ---- FALLBACK: proven round-3 flag poll, then fresh reload ----
    if (!ok){
      if (t > 0 && lane == 0){
        while (__hip_atomic_load(pollp, __ATOMIC_RELAXED, __HIP_MEMORY_SCOPE_AGENT) < t) { }
      }
      __builtin_amdgcn_sched_barrier(0);
#pragma unroll
      for (int ks = 0; ks < 4; ks++)
#pragma unroll
        for (int j = 0; j < 4; j++)
          q[ks*4 + j] = __hip_atomic_load(hp + ks*16 + j, __ATOMIC_RELAXED, __HIP_MEMORY_SCOPE_AGENT);
    }
    __builtin_amdgcn_sched_barrier(0);

    // ---- extract bf16 fragments (high 16 bits of each tagged f32) ----
    short8 hv[4];
#pragma unroll
    for (int ks = 0; ks < 4; ks++){
      union { short8 v; u16 s[8]; } hb;
#pragma unroll
      for (int e = 0; e < 8; e++){
        u64 qv = q[ks*4 + (e >> 1)];
        u32 w = (u32)(qv >> (32 * (e & 1)));
        hb.s[e] = (u16)(w >> 16);
      }
      hv[ks] = hb.v;
    }

    f32x4 acc[8] = {};
#pragma unroll
    for (int ks = 0; ks < 4; ks++)
#pragma unroll
      for (int nf = 0; nf < 8; nf++)
        acc[nf] = __builtin_amdgcn_mfma_f32_16x16x32_bf16(hv[ks], wf[nf][ks], acc[nf], 0, 0, 0);

    // ---- k-split partials -> LDS (swizzled) ----
#pragma unroll
    for (int nf = 0; nf < 8; nf++)
#pragma unroll
      for (int r = 0; r < 4; r++)
        part[wv][rq + r][(nf*16 + fr) ^ sw_w] = acc[nf][r];
    __syncthreads();

    // ---- reduce 8 partials + g, tanh, stores ----
    float s[4] = { g4[0], g4[1], g4[2], g4[3] };
#pragma unroll
    for (int w = 0; w < 8; w++){
      f32x4 p = *reinterpret_cast<f32x4*>(&part[w][row][c4 ^ sw_r]);
#pragma unroll
      for (int j = 0; j < 4; j++) s[j] += p[j];
    }
    float hv4[4];
#pragma unroll
    for (int j = 0; j < 4; j++) hv4[j] = tanhf(s[j]);
    f32x4 ov = { hv4[0], hv4[1], hv4[2], hv4[3] };
    *reinterpret_cast<f32x4*>(&outp[gaddr]) = ov;

    const u32 ntag = (u32)(t + 1);
    u32 w0 = ((u32)f2bf(hv4[0]) << 16) | ntag;
    u32 w1 = ((u32)f2bf(hv4[1]) << 16) | ntag;
    u32 w2 = ((u32)f2bf(hv4[2]) << 16) | ntag;
    u32 w3 = ((u32)f2bf(hv4[3]) << 16) | ntag;
    u64* hd = (u64*)(Hf + (long)((t + 1) & 1)*(Bb*Hh) + (long)(b0 + row)*Hh + n0 + c4);
    __hip_atomic_store(hd + 0, (u64)w0 | ((u64)w1 << 32),
                       __ATOMIC_RELAXED, __HIP_MEMORY_SCOPE_AGENT);
    __hip_atomic_store(hd + 1, (u64)w2 | ((u64)w3 << 32),
                       __ATOMIC_RELAXED, __HIP_MEMORY_SCOPE_AGENT);
    if (t == Tt - 1)
      *reinterpret_cast<f32x4*>(&hT[(long)(b0 + row)*Hh + n0 + c4]) = ov;

    // ---- proven release: drain -> barrier -> flag (needed by fallback) ----
    asm volatile("s_waitcnt vmcnt(0)" ::: "memory");
    __syncthreads();
    if (tid == 0)
      __hip_atomic_store(myflag, t + 1, __ATOMIC_RELAXED, __HIP_MEMORY_SCOPE_AGENT);
  }
}

extern "C" void kernel_launch(void* const* d_in, const int* in_sizes, int n_in,
                              void* d_out, int out_size, void* d_ws, size_t ws_size,
                              hipStream_t stream){
  (void)in_sizes; (void)n_in; (void)out_size; (void)ws_size;
  const float* x  = (const float*)d_in[0];
  const float* h0 = (const float*)d_in[1];
  const float* c0 = (const float*)d_in[2];
  const float* Wx = (const float*)d_in[3];
  const float* bx = (const float*)d_in[4];
  const float* Uc = (const float*)d_in[5];
  const float* Vh = (const float*)d_in[6];

  float* out = (float*)d_out;
  float* hT  = out + (long)Bb*Tt*Hh;
  float* cT  = hT + (long)Bb*Hh;

  u16* xcb  = (u16*)d_ws;                       // 32768 x 512 bf16 (xc, then c in place)
  u16* xb   = xcb + (long)32768*512;            // 32768 x 1024 bf16
  u16* wxb  = xb  + (long)32768*1024;           // 512 x 1024
  u16* ucb  = wxb + (long)512*1024;             // 1024 x 512
  u16* vhb  = ucb + (long)1024*512;             // 1024 x 1024
  float* hff = (float*)(vhb + (long)1024*1024); // 2 x 64 x 1024 f32 tagged h
  int* flags = (int*)(hff + 2L*Bb*Hh);          // 32 flags, padded x32

  hipMemsetAsync(flags, 0, 32*32*sizeof(int), stream);

  cvt_kernel<<<2048, 256, 0, stream>>>(x,  xb,  (long)32768*1024/4);
  cvt_kernel<<<512,  256, 0, stream>>>(Wx, wxb, (long)512*1024/4);
  cvt_kernel<<<512,  256, 0, stream>>>(Uc, ucb, (long)1024*512/4);
  cvt_kernel<<<1024, 256, 0, stream>>>(Vh, vhb, (long)1024*1024/4);
  hinit_kernel<<<128, 256, 0, stream>>>(h0, hff);   // tagged h_0 + sentinel buf1

  // xc = x @ Wx^T + bx  -> bf16
  gemm_nt<<<dim3(256, 4), 256, 0, stream>>>(xb, wxb, nullptr, xcb, bx, 32768, 512, 1024, 1);
  // c_t (in place), c_T
  ema_kernel<<<256, 128, 0, stream>>>(xcb, c0, cT);
  // g = c @ Uc^T -> f32 straight into d_out (consumed in place by recurrence)
  gemm_nt<<<dim3(256, 8), 256, 0, stream>>>(xcb, ucb, out, nullptr, nullptr, 32768, 1024, 512, 0);
  // h_t = tanh(g_t + h_{t-1} @ Vh^T), persistent, hybrid tag/flag sync
  recur_kernel<<<32, 512, 0, stream>>>(vhb, hff, out, hT, flags);
}

// Round 9
// 2205.582 us; speedup vs baseline: 1.3680x; 1.3680x over previous
//
#include <hip/hip_runtime.h>
#include <hip/hip_bf16.h>

typedef unsigned short u16;
typedef unsigned long long u64;
typedef __attribute__((ext_vector_type(8))) short short8;
typedef __attribute__((ext_vector_type(4))) float f32x4;
typedef __attribute__((ext_vector_type(4))) unsigned short u16x4;

constexpr int Bb = 64, Tt = 512, INi = 1024, Hh = 1024, Cc = 512;

__device__ inline u16 f2bf(float f){
  unsigned u = __float_as_uint(f);
  u += 0x7FFF + ((u >> 16) & 1);          // RTNE
  return (u16)(u >> 16);
}
__device__ inline float bf2f(u16 v){ return __uint_as_float(((unsigned)v) << 16); }

// ---------------- f32 -> bf16 bulk convert ----------------
__global__ void cvt_kernel(const float* __restrict__ in, u16* __restrict__ outp, long n4){
  long i = (long)blockIdx.x * blockDim.x + threadIdx.x;
  const long stride = (long)gridDim.x * blockDim.x;
  for (; i < n4; i += stride){
    float4 v = reinterpret_cast<const float4*>(in)[i];
    u16x4 o = { f2bf(v.x), f2bf(v.y), f2bf(v.z), f2bf(v.w) };
    reinterpret_cast<u16x4*>(outp)[i] = o;
  }
}

// ---------------- bf16 NT GEMM: C[m][n] = sum_k A[m][k]*B[n][k] ----------------
// 128x128 tile, BK=32, 4 waves each 64x64 (4x4 16x16x32 frags)
__global__ __launch_bounds__(256) void gemm_nt(
  const u16* __restrict__ A, const u16* __restrict__ Bm,
  float* __restrict__ Cf, u16* __restrict__ Cb, const float* __restrict__ bias,
  int M, int N, int K, int write_bf16)
{
  __shared__ u16 Als[128][32];
  __shared__ u16 Bls[128][32];
  const int tid  = threadIdx.x;
  const long m0  = (long)blockIdx.x * 128;
  const long n0  = (long)blockIdx.y * 128;
  const int wave = tid >> 6, lane = tid & 63;
  const int wm = (wave >> 1) * 64, wn = (wave & 1) * 64;
  const int r0 = tid >> 2, c8 = (tid & 3) * 8;
  const int fr = lane & 15, kq = (lane >> 4) * 8;
  f32x4 acc[4][4] = {};
#pragma unroll 1
  for (int k0 = 0; k0 < K; k0 += 32){
    *(short8*)(&Als[r0][c8])      = *(const short8*)(&A[(m0 + r0)*K + k0 + c8]);
    *(short8*)(&Als[r0 + 64][c8]) = *(const short8*)(&A[(m0 + r0 + 64)*K + k0 + c8]);
    *(short8*)(&Bls[r0][c8])      = *(const short8*)(&Bm[(n0 + r0)*K + k0 + c8]);
    *(short8*)(&Bls[r0 + 64][c8]) = *(const short8*)(&Bm[(n0 + r0 + 64)*K + k0 + c8]);
    __syncthreads();
    short8 af[4], bfv[4];
#pragma unroll
    for (int i = 0; i < 4; i++) af[i]  = *(const short8*)(&Als[wm + i*16 + fr][kq]);
#pragma unroll
    for (int i = 0; i < 4; i++) bfv[i] = *(const short8*)(&Bls[wn + i*16 + fr][kq]);
#pragma unroll
    for (int mi = 0; mi < 4; mi++)
#pragma unroll
      for (int ni = 0; ni < 4; ni++)
        acc[mi][ni] = __builtin_amdgcn_mfma_f32_16x16x32_bf16(af[mi], bfv[ni], acc[mi][ni], 0, 0, 0);
    __syncthreads();
  }
  const int rq = (lane >> 4) * 4;
#pragma unroll
  for (int mi = 0; mi < 4; mi++)
#pragma unroll
    for (int ni = 0; ni < 4; ni++)
#pragma unroll
      for (int r = 0; r < 4; r++){
        long gm = m0 + wm + mi*16 + rq + r;
        long gn = n0 + wn + ni*16 + fr;
        float v = acc[mi][ni][r];
        if (write_bf16) Cb[gm*N + gn] = f2bf(v + bias[gn]);
        else            Cf[gm*N + gn] = v;
      }
}

// ---------------- in-place EMA over time: xcb <- c_t (bf16), cT f32 ----------------
__global__ __launch_bounds__(128) void ema_kernel(u16* __restrict__ xcb,
                                                  const float* __restrict__ c0,
                                                  float* __restrict__ cT){
  const int b = blockIdx.x >> 2;
  const int c = ((blockIdx.x & 3) * 128) + threadIdx.x;
  float run = c0[b*Cc + c];
  u16* p = xcb + (long)b*Tt*Cc + c;
#pragma unroll 1
  for (int t = 0; t < Tt; t += 8){
    u16 v[8];
#pragma unroll
    for (int u = 0; u < 8; u++) v[u] = p[(long)(t + u)*Cc];
#pragma unroll
    for (int u = 0; u < 8; u++){
      run = 0.05f*run + 0.95f*bf2f(v[u]);
      p[(long)(t + u)*Cc] = f2bf(run);
    }
  }
  cT[b*Cc + c] = run;
}

// ---------------- persistent recurrent kernel ----------------
// Round-3 skeleton (1760us proven) with the barrier drains removed from the
// recurrence-critical path:
//  - mid barrier: raw s_barrier + lgkmcnt(0) only (no vmem drain)
//  - tail: bf16 h-store (LLC) -> vmcnt(0) (waits ONLY that store) ->
//    raw s_barrier -> flag; the f32 out-store + hT are issued AFTER the flag
//    and complete under the next step's poll (they are never read by peers).
__global__ __launch_bounds__(512, 2) void recur_kernel(
  const u16* __restrict__ Vhb, u16* __restrict__ Hbuf,
  float* __restrict__ outp, float* __restrict__ hT, int* __restrict__ flags)
{
  const int tid = threadIdx.x;
  const int wv = tid >> 6, lane = tid & 63;
  const int bid = blockIdx.x;
  const int b0 = (bid >> 3) * 16;     // batch rows
  const int n0 = (bid & 7) * 128;     // h columns owned (output)
  const int fr = lane & 15, kq = (lane >> 4) * 8;
  const int rq = (lane >> 4) * 4;
  const int kbase = wv * 128;         // this wave's k-slice
  const int sw_w = rq << 1;           // write-side XOR swizzle

  // Vh fragments [nf][ks] (round-3 proven load pattern)
  short8 wf[8][4];
#pragma unroll
  for (int nf = 0; nf < 8; nf++)
#pragma unroll
    for (int ks = 0; ks < 4; ks++)
      wf[nf][ks] = *(const short8*)(&Vhb[(long)(n0 + nf*16 + fr)*Hh + kbase + ks*32 + kq]);

  __shared__ float part[8][16][128];  // 64 KiB

  const int row = tid >> 5;           // 0..15
  const int c4  = (tid & 31) * 4;     // 0..124
  const int sw_r = (row & 12) << 1;
  int* pollp  = &flags[((bid & ~7) | wv) * 32];   // producer of my k-slice
  int* myflag = &flags[bid * 32];

#pragma unroll 1
  for (int t = 0; t < Tt; t++){
    // ---- prefetch g = (c@Uc^T)[b,t,:]: HBM latency hides under the spin ----
    const long gaddr = ((long)(b0 + row)*Tt + t)*Hh + n0 + c4;
    const f32x4 g4 = *reinterpret_cast<const f32x4*>(&outp[gaddr]);

    // ---- wait for THIS wave's 1 producer block ----
    if (t > 0 && lane == 0){
      while (__hip_atomic_load(pollp, __ATOMIC_RELAXED, __HIP_MEMORY_SCOPE_AGENT) < t) { }
    }
    __builtin_amdgcn_sched_barrier(0);

    // ---- load h_{t-1} k-slice (LLC-direct atomics) ----
    const u16* Hp = Hbuf + (t & 1) * (Bb * Hh);
    const u16* hp = &Hp[(long)(b0 + fr)*Hh + kbase + kq];
    short8 hv[4];
#pragma unroll
    for (int ks = 0; ks < 4; ks++){
      union { u64 q[2]; short8 v; } cv;
      const u64* hp64 = (const u64*)(hp + ks*32);
      cv.q[0] = __hip_atomic_load(hp64 + 0, __ATOMIC_RELAXED, __HIP_MEMORY_SCOPE_AGENT);
      cv.q[1] = __hip_atomic_load(hp64 + 1, __ATOMIC_RELAXED, __HIP_MEMORY_SCOPE_AGENT);
      hv[ks] = cv.v;
    }

    f32x4 acc[8] = {};
#pragma unroll
    for (int ks = 0; ks < 4; ks++)
#pragma unroll
      for (int nf = 0; nf < 8; nf++)
        acc[nf] = __builtin_amdgcn_mfma_f32_16x16x32_bf16(hv[ks], wf[nf][ks], acc[nf], 0, 0, 0);

    // ---- k-split partials -> LDS (swizzled) ----
#pragma unroll
    for (int nf = 0; nf < 8; nf++)
#pragma unroll
      for (int r = 0; r < 4; r++)
        part[wv][rq + r][(nf*16 + fr) ^ sw_w] = acc[nf][r];

    // ---- mid barrier: order LDS writes only (no vmem drain) ----
    asm volatile("s_waitcnt lgkmcnt(0)" ::: "memory");
    __builtin_amdgcn_s_barrier();
    __builtin_amdgcn_sched_barrier(0);

    // ---- reduce 8 partials + g, tanh ----
    float s[4] = { g4[0], g4[1], g4[2], g4[3] };
#pragma unroll
    for (int w = 0; w < 8; w++){
      f32x4 p = *reinterpret_cast<f32x4*>(&part[w][row][c4 ^ sw_r]);
#pragma unroll
      for (int j = 0; j < 4; j++) s[j] += p[j];
    }
    float hv4[4];
#pragma unroll
    for (int j = 0; j < 4; j++) hv4[j] = tanhf(s[j]);

    // ---- recurrence-critical: h-store (bf16, LLC) -> drain IT ONLY ->
    //      raw barrier (all waves' reduce-reads done, h-stores committed) ->
    //      flag. f32 stores deferred past the flag.
    u16* Hn = Hbuf + ((t + 1) & 1) * (Bb * Hh);
    u64 pk = (u64)f2bf(hv4[0]) | ((u64)f2bf(hv4[1]) << 16)
           | ((u64)f2bf(hv4[2]) << 32) | ((u64)f2bf(hv4[3]) << 48);
    __hip_atomic_store((u64*)(&Hn[(long)(b0 + row)*Hh + n0 + c4]), pk,
                       __ATOMIC_RELAXED, __HIP_MEMORY_SCOPE_AGENT);
    asm volatile("s_waitcnt vmcnt(0)" ::: "memory");   // only the h-store is outstanding
    __builtin_amdgcn_s_barrier();
    __builtin_amdgcn_sched_barrier(0);
    if (tid == 0)
      __hip_atomic_store(myflag, t + 1, __ATOMIC_RELAXED, __HIP_MEMORY_SCOPE_AGENT);
    __builtin_amdgcn_sched_barrier(0);

    // ---- deferred stores: complete under the next step's poll ----
    f32x4 ov = { hv4[0], hv4[1], hv4[2], hv4[3] };
    *reinterpret_cast<f32x4*>(&outp[gaddr]) = ov;
    if (t == Tt - 1)
      *reinterpret_cast<f32x4*>(&hT[(long)(b0 + row)*Hh + n0 + c4]) = ov;
  }
}

extern "C" void kernel_launch(void* const* d_in, const int* in_sizes, int n_in,
                              void* d_out, int out_size, void* d_ws, size_t ws_size,
                              hipStream_t stream){
  (void)in_sizes; (void)n_in; (void)out_size; (void)ws_size;
  const float* x  = (const float*)d_in[0];
  const float* h0 = (const float*)d_in[1];
  const float* c0 = (const float*)d_in[2];
  const float* Wx = (const float*)d_in[3];
  const float* bx = (const float*)d_in[4];
  const float* Uc = (const float*)d_in[5];
  const float* Vh = (const float*)d_in[6];

  float* out = (float*)d_out;
  float* hT  = out + (long)Bb*Tt*Hh;
  float* cT  = hT + (long)Bb*Hh;

  u16* xcb  = (u16*)d_ws;                     // 32768 x 512 bf16 (xc, then c in place)
  u16* xb   = xcb + (long)32768*512;          // 32768 x 1024 bf16
  u16* wxb  = xb  + (long)32768*1024;         // 512 x 1024
  u16* ucb  = wxb + (long)512*1024;           // 1024 x 512
  u16* vhb  = ucb + (long)1024*512;           // 1024 x 1024
  u16* hbuf = vhb + (long)1024*1024;          // 2 x 64 x 1024 (double buffer)
  int* flags = (int*)(hbuf + 2L*Bb*Hh);       // 32 flags, padded x32 (128B lines)

  hipMemsetAsync(flags, 0, 32*32*sizeof(int), stream);

  cvt_kernel<<<2048, 256, 0, stream>>>(x,  xb,  (long)32768*1024/4);
  cvt_kernel<<<512,  256, 0, stream>>>(Wx, wxb, (long)512*1024/4);
  cvt_kernel<<<512,  256, 0, stream>>>(Uc, ucb, (long)1024*512/4);
  cvt_kernel<<<1024, 256, 0, stream>>>(Vh, vhb, (long)1024*1024/4);
  cvt_kernel<<<64,   256, 0, stream>>>(h0, hbuf, (long)Bb*Hh/4);   // H buffer 0 = h_0

  // xc = x @ Wx^T + bx  -> bf16
  gemm_nt<<<dim3(256, 4), 256, 0, stream>>>(xb, wxb, nullptr, xcb, bx, 32768, 512, 1024, 1);
  // c_t (in place), c_T
  ema_kernel<<<256, 128, 0, stream>>>(xcb, c0, cT);
  // g = c @ Uc^T -> f32 straight into d_out (consumed in place by recurrence)
  gemm_nt<<<dim3(256, 8), 256, 0, stream>>>(xcb, ucb, out, nullptr, nullptr, 32768, 1024, 512, 0);
  // h_t = tanh(g_t + h_{t-1} @ Vh^T), persistent, 512 steps
  recur_kernel<<<32, 512, 0, stream>>>(vhb, hbuf, out, hT, flags);
}

// Round 10
// 1614.983 us; speedup vs baseline: 1.8682x; 1.3657x over previous
//
#include <hip/hip_runtime.h>
#include <hip/hip_bf16.h>

typedef unsigned short u16;
typedef unsigned long long u64;
typedef __attribute__((ext_vector_type(8))) short short8;
typedef __attribute__((ext_vector_type(4))) float f32x4;
typedef __attribute__((ext_vector_type(4))) unsigned short u16x4;

constexpr int Bb = 64, Tt = 512, INi = 1024, Hh = 1024, Cc = 512;

__device__ inline u16 f2bf(float f){
  unsigned u = __float_as_uint(f);
  u += 0x7FFF + ((u >> 16) & 1);          // RTNE
  return (u16)(u >> 16);
}
__device__ inline float bf2f(u16 v){ return __uint_as_float(((unsigned)v) << 16); }

// ---------------- f32 -> bf16 bulk convert ----------------
__global__ void cvt_kernel(const float* __restrict__ in, u16* __restrict__ outp, long n4){
  long i = (long)blockIdx.x * blockDim.x + threadIdx.x;
  const long stride = (long)gridDim.x * blockDim.x;
  for (; i < n4; i += stride){
    float4 v = reinterpret_cast<const float4*>(in)[i];
    u16x4 o = { f2bf(v.x), f2bf(v.y), f2bf(v.z), f2bf(v.w) };
    reinterpret_cast<u16x4*>(outp)[i] = o;
  }
}

// ---------------- bf16 NT GEMM: C[m][n] = sum_k A[m][k]*B[n][k] ----------------
// 128x128 tile, BK=32, 4 waves each 64x64 (4x4 16x16x32 frags)
__global__ __launch_bounds__(256) void gemm_nt(
  const u16* __restrict__ A, const u16* __restrict__ Bm,
  float* __restrict__ Cf, u16* __restrict__ Cb, const float* __restrict__ bias,
  int M, int N, int K, int write_bf16)
{
  __shared__ u16 Als[128][32];
  __shared__ u16 Bls[128][32];
  const int tid  = threadIdx.x;
  const long m0  = (long)blockIdx.x * 128;
  const long n0  = (long)blockIdx.y * 128;
  const int wave = tid >> 6, lane = tid & 63;
  const int wm = (wave >> 1) * 64, wn = (wave & 1) * 64;
  const int r0 = tid >> 2, c8 = (tid & 3) * 8;
  const int fr = lane & 15, kq = (lane >> 4) * 8;
  f32x4 acc[4][4] = {};
#pragma unroll 1
  for (int k0 = 0; k0 < K; k0 += 32){
    *(short8*)(&Als[r0][c8])      = *(const short8*)(&A[(m0 + r0)*K + k0 + c8]);
    *(short8*)(&Als[r0 + 64][c8]) = *(const short8*)(&A[(m0 + r0 + 64)*K + k0 + c8]);
    *(short8*)(&Bls[r0][c8])      = *(const short8*)(&Bm[(n0 + r0)*K + k0 + c8]);
    *(short8*)(&Bls[r0 + 64][c8]) = *(const short8*)(&Bm[(n0 + r0 + 64)*K + k0 + c8]);
    __syncthreads();
    short8 af[4], bfv[4];
#pragma unroll
    for (int i = 0; i < 4; i++) af[i]  = *(const short8*)(&Als[wm + i*16 + fr][kq]);
#pragma unroll
    for (int i = 0; i < 4; i++) bfv[i] = *(const short8*)(&Bls[wn + i*16 + fr][kq]);
#pragma unroll
    for (int mi = 0; mi < 4; mi++)
#pragma unroll
      for (int ni = 0; ni < 4; ni++)
        acc[mi][ni] = __builtin_amdgcn_mfma_f32_16x16x32_bf16(af[mi], bfv[ni], acc[mi][ni], 0, 0, 0);
    __syncthreads();
  }
  const int rq = (lane >> 4) * 4;
#pragma unroll
  for (int mi = 0; mi < 4; mi++)
#pragma unroll
    for (int ni = 0; ni < 4; ni++)
#pragma unroll
      for (int r = 0; r < 4; r++){
        long gm = m0 + wm + mi*16 + rq + r;
        long gn = n0 + wn + ni*16 + fr;
        float v = acc[mi][ni][r];
        if (write_bf16) Cb[gm*N + gn] = f2bf(v + bias[gn]);
        else            Cf[gm*N + gn] = v;
      }
}

// ---------------- in-place EMA over time: xcb <- c_t (bf16), cT f32 ----------------
__global__ __launch_bounds__(128) void ema_kernel(u16* __restrict__ xcb,
                                                  const float* __restrict__ c0,
                                                  float* __restrict__ cT){
  const int b = blockIdx.x >> 2;
  const int c = ((blockIdx.x & 3) * 128) + threadIdx.x;
  float run = c0[b*Cc + c];
  u16* p = xcb + (long)b*Tt*Cc + c;
#pragma unroll 1
  for (int t = 0; t < Tt; t += 8){
    u16 v[8];
#pragma unroll
    for (int u = 0; u < 8; u++) v[u] = p[(long)(t + u)*Cc];
#pragma unroll
    for (int u = 0; u < 8; u++){
      run = 0.05f*run + 0.95f*bf2f(v[u]);
      p[(long)(t + u)*Cc] = f2bf(run);
    }
  }
  cT[b*Cc + c] = run;
}

// ---------------- persistent recurrent kernel ----------------
// EXACT round-3 skeleton (1760us proven) with ONE change: the h_{t-1} k-slice
// load is a single inline-asm block of 4 back-to-back global_load_dwordx4 sc1
// with ONE s_waitcnt -- instead of a 4-iteration loop of u64 atomic loads that
// the compiler serialized with a per-iteration vmcnt wait (~4 LLC RTs -> 1).
__global__ __launch_bounds__(512, 2) void recur_kernel(
  const u16* __restrict__ Vhb, u16* __restrict__ Hbuf,
  float* __restrict__ outp, float* __restrict__ hT, int* __restrict__ flags)
{
  const int tid = threadIdx.x;
  const int wv = tid >> 6, lane = tid & 63;
  const int bid = blockIdx.x;
  const int b0 = (bid >> 3) * 16;     // batch rows
  const int n0 = (bid & 7) * 128;     // h columns owned (output)
  const int fr = lane & 15, kq = (lane >> 4) * 8;
  const int rq = (lane >> 4) * 4;
  const int kbase = wv * 128;         // this wave's k-slice
  const int sw_w = rq << 1;           // write-side XOR swizzle

  // Vh fragments, register-stationary: [nf 0..7][ks 0..3]
  short8 wf[8][4];
#pragma unroll
  for (int nf = 0; nf < 8; nf++)
#pragma unroll
    for (int ks = 0; ks < 4; ks++)
      wf[nf][ks] = *(const short8*)(&Vhb[(long)(n0 + nf*16 + fr)*Hh + kbase + ks*32 + kq]);

  __shared__ float part[8][16][128];  // 64 KiB, XOR-swizzled columns

  const int row = tid >> 5;           // 0..15
  const int c4  = (tid & 31) * 4;     // 0..124
  const int sw_r = (row & 12) << 1;
  int* pollp  = &flags[((bid & ~7) | wv) * 32];   // producer of my k-slice
  int* myflag = &flags[bid * 32];

#pragma unroll 1
  for (int t = 0; t < Tt; t++){
    // ---- prefetch g = (c@Uc^T)[b,t,:] early: HBM latency hides under spin ----
    const long gaddr = ((long)(b0 + row)*Tt + t)*Hh + n0 + c4;
    const f32x4 g4 = *reinterpret_cast<const f32x4*>(&outp[gaddr]);

    // ---- wait for THIS wave's 1 producer block ----
    if (t > 0 && lane == 0){
      while (__hip_atomic_load(pollp, __ATOMIC_RELAXED, __HIP_MEMORY_SCOPE_AGENT) < t) { }
    }
    __builtin_amdgcn_sched_barrier(0);

    // ---- load h_{t-1} k-slice: 4x dwordx4 sc1 batched, ONE waitcnt (1 RT) ----
    const u16* Hp = Hbuf + (t & 1) * (Bb * Hh);
    const u16* hp = &Hp[(long)(b0 + fr)*Hh + kbase + kq];
    short8 hv[4];
    asm volatile(
      "global_load_dwordx4 %0, %4, off sc1\n\t"
      "global_load_dwordx4 %1, %5, off sc1\n\t"
      "global_load_dwordx4 %2, %6, off sc1\n\t"
      "global_load_dwordx4 %3, %7, off sc1\n\t"
      "s_waitcnt vmcnt(0)"
      : "=&v"(hv[0]), "=&v"(hv[1]), "=&v"(hv[2]), "=&v"(hv[3])
      : "v"(hp), "v"(hp + 32), "v"(hp + 64), "v"(hp + 96)
      : "memory");
    __builtin_amdgcn_sched_barrier(0);

    f32x4 acc[8] = {};
#pragma unroll
    for (int ks = 0; ks < 4; ks++)
#pragma unroll
      for (int nf = 0; nf < 8; nf++)
        acc[nf] = __builtin_amdgcn_mfma_f32_16x16x32_bf16(hv[ks], wf[nf][ks], acc[nf], 0, 0, 0);

    // ---- k-split partial sums -> LDS (swizzled: 2-way max on write) ----
#pragma unroll
    for (int nf = 0; nf < 8; nf++)
#pragma unroll
      for (int r = 0; r < 4; r++)
        part[wv][rq + r][(nf*16 + fr) ^ sw_w] = acc[nf][r];
    __syncthreads();

    // ---- reduce 8 partials + g, tanh, store out / h_next ----
    float s[4] = { g4[0], g4[1], g4[2], g4[3] };
#pragma unroll
    for (int w = 0; w < 8; w++){
      f32x4 p = *reinterpret_cast<f32x4*>(&part[w][row][c4 ^ sw_r]);
#pragma unroll
      for (int j = 0; j < 4; j++) s[j] += p[j];
    }
    float hv4[4];
#pragma unroll
    for (int j = 0; j < 4; j++) hv4[j] = tanhf(s[j]);
    *reinterpret_cast<f32x4*>(&outp[gaddr]) = (f32x4){ hv4[0], hv4[1], hv4[2], hv4[3] };
    u16* Hn = Hbuf + ((t + 1) & 1) * (Bb * Hh);
    u64 pk = (u64)f2bf(hv4[0]) | ((u64)f2bf(hv4[1]) << 16)
           | ((u64)f2bf(hv4[2]) << 32) | ((u64)f2bf(hv4[3]) << 48);
    __hip_atomic_store((u64*)(&Hn[(long)(b0 + row)*Hh + n0 + c4]), pk,
                       __ATOMIC_RELAXED, __HIP_MEMORY_SCOPE_AGENT);
    if (t == Tt - 1)
      *reinterpret_cast<f32x4*>(&hT[(long)(b0 + row)*Hh + n0 + c4]) =
        (f32x4){ hv4[0], hv4[1], hv4[2], hv4[3] };
    __syncthreads();   // drains vmcnt: all sc1 h-stores complete at LLC
    if (tid == 0)
      __hip_atomic_store(myflag, t + 1, __ATOMIC_RELAXED, __HIP_MEMORY_SCOPE_AGENT);
  }
}

extern "C" void kernel_launch(void* const* d_in, const int* in_sizes, int n_in,
                              void* d_out, int out_size, void* d_ws, size_t ws_size,
                              hipStream_t stream){
  (void)in_sizes; (void)n_in; (void)out_size; (void)ws_size;
  const float* x  = (const float*)d_in[0];
  const float* h0 = (const float*)d_in[1];
  const float* c0 = (const float*)d_in[2];
  const float* Wx = (const float*)d_in[3];
  const float* bx = (const float*)d_in[4];
  const float* Uc = (const float*)d_in[5];
  const float* Vh = (const float*)d_in[6];

  float* out = (float*)d_out;
  float* hT  = out + (long)Bb*Tt*Hh;
  float* cT  = hT + (long)Bb*Hh;

  u16* xcb  = (u16*)d_ws;                     // 32768 x 512 bf16 (xc, then c in place)
  u16* xb   = xcb + (long)32768*512;          // 32768 x 1024 bf16
  u16* wxb  = xb  + (long)32768*1024;         // 512 x 1024
  u16* ucb  = wxb + (long)512*1024;           // 1024 x 512
  u16* vhb  = ucb + (long)1024*512;           // 1024 x 1024
  u16* hbuf = vhb + (long)1024*1024;          // 2 x 64 x 1024 (double buffer)
  int* flags = (int*)(hbuf + 2L*Bb*Hh);       // 32 flags, padded x32 (128B lines)

  hipMemsetAsync(flags, 0, 32*32*sizeof(int), stream);

  cvt_kernel<<<2048, 256, 0, stream>>>(x,  xb,  (long)32768*1024/4);
  cvt_kernel<<<512,  256, 0, stream>>>(Wx, wxb, (long)512*1024/4);
  cvt_kernel<<<512,  256, 0, stream>>>(Uc, ucb, (long)1024*512/4);
  cvt_kernel<<<1024, 256, 0, stream>>>(Vh, vhb, (long)1024*1024/4);
  cvt_kernel<<<64,   256, 0, stream>>>(h0, hbuf, (long)Bb*Hh/4);   // H buffer 0 = h_0

  // xc = x @ Wx^T + bx  -> bf16
  gemm_nt<<<dim3(256, 4), 256, 0, stream>>>(xb, wxb, nullptr, xcb, bx, 32768, 512, 1024, 1);
  // c_t (in place), c_T
  ema_kernel<<<256, 128, 0, stream>>>(xcb, c0, cT);
  // g = c @ Uc^T -> f32 straight into d_out (consumed in place by recurrence)
  gemm_nt<<<dim3(256, 8), 256, 0, stream>>>(xcb, ucb, out, nullptr, nullptr, 32768, 1024, 512, 0);
  // h_t = tanh(g_t + h_{t-1} @ Vh^T), persistent, 512 steps
  recur_kernel<<<32, 512, 0, stream>>>(vhb, hbuf, out, hT, flags);
}